// Round 1
// baseline (34.307 us; speedup 1.0000x reference)
//
#include <hip/hip_runtime.h>
#include <hip/hip_bf16.h>

#define BATCH 16384
#define HIST 50
#define GROUPS_PER_BLOCK 16   // 16 lanes per batch element, 256 threads/block

// out[b] = sigmoid( sum_l z_l * w_l + u_e . y_e ),  z = softmax(w),
// w_l = item_emb[X[b,l]] . item_emb[y[b]]   (BETA=ALPHA=1)
__global__ __launch_bounds__(256, 4) void RUM_72980084294375_kernel(
    const int* __restrict__ u, const int* __restrict__ X, const int* __restrict__ y,
    const float* __restrict__ item_emb, const float* __restrict__ user_emb,
    float* __restrict__ out)
{
    __shared__ int sX[GROUPS_PER_BLOCK][HIST];

    const int tid = threadIdx.x;
    const int block_b0 = blockIdx.x * GROUPS_PER_BLOCK;

    // Cooperative, coalesced load of this block's 16x50 history indices.
    for (int i = tid; i < GROUPS_PER_BLOCK * HIST; i += 256) {
        sX[i / HIST][i % HIST] = X[block_b0 * HIST + i];
    }
    __syncthreads();

    const int g    = tid >> 4;   // batch element within block
    const int lane = tid & 15;   // quarter-wave lane; owns float4 slice of E=64
    const int b    = block_b0 + g;

    const float4* item4 = reinterpret_cast<const float4*>(item_emb);
    const float4* user4 = reinterpret_cast<const float4*>(user_emb);

    const int yi = y[b];
    const int ui = u[b];
    const float4 y4 = item4[yi * 16 + lane];
    const float4 u4 = user4[ui * 16 + lane];

    float uy = u4.x * y4.x + u4.y * y4.y + u4.z * y4.z + u4.w * y4.w;
    #pragma unroll
    for (int m = 1; m < 16; m <<= 1) uy += __shfl_xor(uy, m, 16);

    // Online softmax-weighted mean of w (branch-free).
    float mx = -1e30f, s = 0.0f, t = 0.0f;
    #pragma unroll 5
    for (int l = 0; l < HIST; ++l) {
        const int idx = sX[g][l];
        const float4 x4 = item4[idx * 16 + lane];
        float w = x4.x * y4.x + x4.y * y4.y + x4.z * y4.z + x4.w * y4.w;
        #pragma unroll
        for (int m = 1; m < 16; m <<= 1) w += __shfl_xor(w, m, 16);
        const float mn   = fmaxf(mx, w);
        const float corr = __expf(mx - mn);
        const float e    = __expf(w - mn);
        s = s * corr + e;
        t = t * corr + e * w;
        mx = mn;
    }

    if (lane == 0) {
        const float logit = t / s + uy;
        out[b] = 1.0f / (1.0f + __expf(-logit));
    }
}

extern "C" void kernel_launch(void* const* d_in, const int* in_sizes, int n_in,
                              void* d_out, int out_size, void* d_ws, size_t ws_size,
                              hipStream_t stream) {
    const int*   u        = (const int*)d_in[0];
    const int*   X        = (const int*)d_in[1];
    const int*   y        = (const int*)d_in[2];
    const float* item_emb = (const float*)d_in[3];
    const float* user_emb = (const float*)d_in[4];
    float*       out      = (float*)d_out;

    const int blocks = BATCH / GROUPS_PER_BLOCK;  // 1024
    RUM_72980084294375_kernel<<<blocks, 256, 0, stream>>>(
        u, X, y, item_emb, user_emb, out);
}